// Round 4
// baseline (46.497 us; speedup 1.0000x reference)
//
#include <hip/hip_runtime.h>
#include <math.h>

#define N 2048
#define D 64
#define KP 4

typedef unsigned int uint;
typedef unsigned short ushort;
typedef unsigned long long u64;
typedef __attribute__((ext_vector_type(8))) short bf16x8;
typedef __attribute__((ext_vector_type(4))) float f32x4;
typedef __attribute__((ext_vector_type(4))) uint uint4v;

// float -> bf16 round-to-nearest-even
__device__ __forceinline__ ushort f2bf(float f) {
  uint u = __builtin_bit_cast(uint, f);
  u += 0x7FFFu + ((u >> 16) & 1u);
  return (ushort)(u >> 16);
}

// Mask layout: per row, 8 chunks of 256 cols; each chunk = 4 u64 words.
// Bit l of word j  <->  col = chunk*256 + 4*l + j.

// ---------------- Kernel 1: masks + EA + feat + Fn_bf16 + attr_prob -------
// One block (4 waves) per row. Wave w handles chunks {2w, 2w+1} with
// float4 loads (16B/lane); ballots build the packed masks; the one-hop
// words are reused in-register for the neighbor gather (lane = dim).
__global__ __launch_bounds__(256) void row_kernel(
    const float* __restrict__ attr, const float* __restrict__ edges,
    const float* __restrict__ two_hop, const float* __restrict__ persona,
    const int* __restrict__ timesP, const float* __restrict__ rp,
    const float* __restrict__ Wp, ushort* __restrict__ Fnb,
    u64* __restrict__ ME, u64* __restrict__ MT, float* __restrict__ out)
{
  __shared__ float part[4][64];

  int t = threadIdx.x;
  int w = t >> 6, l = t & 63;
  int row = blockIdx.x;

  const float4* erow4 = reinterpret_cast<const float4*>(edges + (size_t)row * N);
  const float4* trow4 = reinterpret_cast<const float4*>(two_hop + (size_t)row * N);

  u64 mw[2][4];
  #pragma unroll
  for (int cc = 0; cc < 2; ++cc) {
    int chunk = 2 * w + cc;
    float4 ev = erow4[chunk * 64 + l];
    float4 tv = trow4[chunk * 64 + l];
    int colb = chunk * 256 + 4 * l;
    float evs[4] = {ev.x, ev.y, ev.z, ev.w};
    float tvs[4] = {tv.x, tv.y, tv.z, tv.w};
    #pragma unroll
    for (int jj = 0; jj < 4; ++jj) {
      bool eb = evs[jj] != 0.0f;
      u64 meb = __ballot(eb);
      u64 mtb = __ballot((eb || tvs[jj] != 0.0f) && (colb + jj != row));
      mw[cc][jj] = meb;
      if (l == jj) {
        ME[(size_t)row * 32 + chunk * 4 + jj] = meb;
        MT[(size_t)row * 32 + chunk * 4 + jj] = mtb;
      }
    }
  }

  // EA gather: lane l = dimension d
  float acc = 0.0f;
  #pragma unroll
  for (int cc = 0; cc < 2; ++cc) {
    #pragma unroll
    for (int jj = 0; jj < 4; ++jj) {
      u64 word = mw[cc][jj];
      int base = (2 * w + cc) * 256 + jj;
      while (word) {
        int b = __builtin_ctzll(word);
        word &= word - 1;
        acc += attr[(size_t)(base + 4 * b) * D + l];
      }
    }
  }
  part[w][l] = acc;
  __syncthreads();
  float ea = part[0][l] + part[1][l] + part[2][l] + part[3][l];
  __syncthreads();   // before part reuse

  // wave w handles persona component i = w
  float a = attr[(size_t)row * D + l];
  float ri = rp[w], Wi = Wp[w];
  float nf = ri * a + ea * Wi * (1.0f - ri);
  float ss = nf * nf;
  #pragma unroll
  for (int off = 32; off; off >>= 1) ss += __shfl_xor(ss, off);
  float inv = rsqrtf(ss);
  Fnb[((size_t)w * N + row) * D + l] = f2bf(nf * inv);

  int times = timesP[0];
  float p = persona[((size_t)times * N + row) * KP + w];
  float sig = 1.0f / (1.0f + __expf(-nf));
  part[w][l] = p * sig;
  __syncthreads();
  if (w == 0) {
    out[(size_t)N * N + (size_t)row * D + l] =
        part[0][l] + part[1][l] + part[2][l] + part[3][l];
  }
}

// ---------------- Kernel 2: edges_prob via bf16 MFMA ----------------
// 64x64 tile/block, 4 waves, wave (wr,wc) owns a 32x32 quadrant.
// Masks staged to LDS as packed u64 words; straight-line nonlinearity.
__device__ __forceinline__ bf16x8 frag_read(const ushort* buf, int prow, int dbyte) {
  int off = prow * 128 + (dbyte ^ ((prow & 7) << 4));
  return *(const bf16x8*)((const char*)buf + off);
}

__global__ __launch_bounds__(256, 4) void edge_kernel(
    const u64* __restrict__ ME, const u64* __restrict__ MT,
    const float* __restrict__ persona, const int* __restrict__ timesP,
    const float* __restrict__ Tp, const float* __restrict__ ep,
    const ushort* __restrict__ Fnb, float* __restrict__ out)
{
  __shared__ ushort Ab[64 * 64];
  __shared__ ushort Bb[64 * 64];
  __shared__ u64 meL[64][4], mtL[64][4];

  int t = threadIdx.x;
  int w = t >> 6, l = t & 63;
  int wr = w >> 1, wc = w & 1;
  int lr = l >> 4, lc = l & 15;
  int row0 = blockIdx.y * 64;
  int col0 = blockIdx.x * 64;
  int times = timesP[0];

  // stage mask words: 512 u64, each thread loads 2
  {
    int rr = t >> 2, jj = t & 3;
    int cb4 = (col0 >> 8) * 4;
    meL[rr][jj] = ME[(size_t)(row0 + rr) * 32 + cb4 + jj];
    mtL[rr][jj] = MT[(size_t)(row0 + rr) * 32 + cb4 + jj];
  }
  __syncthreads();

  // ---- masks for my 16 elements (MFMA C/D layout) ----
  // global col = col0 + wc*32 + nt*16 + lc -> word j = lc&3,
  // bit = L0 + wc*8 + nt*4 + (lc>>2), L0 = (col0&255)>>2
  uint mem = 0, mtm = 0;
  {
    int j = lc & 3;
    int s0 = ((col0 & 255) >> 2) + wc * 8 + (lc >> 2);
    #pragma unroll
    for (int mt_ = 0; mt_ < 2; ++mt_) {
      #pragma unroll
      for (int jr = 0; jr < 4; ++jr) {
        int rowl = wr * 32 + mt_ * 16 + lr * 4 + jr;
        u64 mew = meL[rowl][j], mtw = mtL[rowl][j];
        #pragma unroll
        for (int nt_ = 0; nt_ < 2; ++nt_) {
          int bp = s0 + nt_ * 4;
          int b = (mt_ * 2 + nt_) * 4 + jr;
          mem |= (uint)((mew >> bp) & 1ull) << b;
          mtm |= (uint)((mtw >> bp) & 1ull) << b;
        }
      }
    }
  }

  // ---- persona for my 2 column tiles, all 4 components ----
  float pc[KP][2];
  #pragma unroll
  for (int i = 0; i < KP; ++i) {
    #pragma unroll
    for (int nt_ = 0; nt_ < 2; ++nt_) {
      int col = col0 + wc * 32 + nt_ * 16 + lc;
      pc[i][nt_] = persona[((size_t)times * N + col) * KP + i];
    }
  }

  f32x4 acc[2][2] = {};

  #pragma unroll
  for (int i = 0; i < KP; ++i) {
    __syncthreads();
    // ---- stage Fn panels (bf16, swizzled) ----
    {
      int r = t >> 2, q = t & 3;
      uint sw = (uint)((r & 7) << 4);
      const char* srcA = (const char*)(Fnb + ((size_t)i * N + row0 + r) * D);
      uint4v a0 = *(const uint4v*)(srcA + q * 32);
      uint4v a1 = *(const uint4v*)(srcA + q * 32 + 16);
      char* dstA = (char*)Ab + r * 128;
      *(uint4v*)(dstA + ((q * 32) ^ sw)) = a0;
      *(uint4v*)(dstA + ((q * 32 + 16) ^ sw)) = a1;
      const char* srcB = (const char*)(Fnb + ((size_t)i * N + col0 + r) * D);
      uint4v b0 = *(const uint4v*)(srcB + q * 32);
      uint4v b1 = *(const uint4v*)(srcB + q * 32 + 16);
      char* dstB = (char*)Bb + r * 128;
      *(uint4v*)(dstB + ((q * 32) ^ sw)) = b0;
      *(uint4v*)(dstB + ((q * 32 + 16) ^ sw)) = b1;
    }
    __syncthreads();

    // ---- S quadrant via MFMA ----
    f32x4 S[2][2] = {};
    #pragma unroll
    for (int ks = 0; ks < 2; ++ks) {
      int dbyte = ks * 64 + lr * 16;
      bf16x8 a0 = frag_read(Ab, wr * 32 + lc, dbyte);
      bf16x8 a1 = frag_read(Ab, wr * 32 + 16 + lc, dbyte);
      bf16x8 b0 = frag_read(Bb, wc * 32 + lc, dbyte);
      bf16x8 b1 = frag_read(Bb, wc * 32 + 16 + lc, dbyte);
      S[0][0] = __builtin_amdgcn_mfma_f32_16x16x32_bf16(a0, b0, S[0][0], 0, 0, 0);
      S[0][1] = __builtin_amdgcn_mfma_f32_16x16x32_bf16(a0, b1, S[0][1], 0, 0, 0);
      S[1][0] = __builtin_amdgcn_mfma_f32_16x16x32_bf16(a1, b0, S[1][0], 0, 0, 0);
      S[1][1] = __builtin_amdgcn_mfma_f32_16x16x32_bf16(a1, b1, S[1][1], 0, 0, 0);
    }

    // ---- straight-line masked nonlinearity ----
    float invT = 1.0f / Tp[i];
    float ei = ep[i];
    float di = ei * __expf(invT);   // e * exp(1/T)
    #pragma unroll
    for (int mt_ = 0; mt_ < 2; ++mt_) {
      #pragma unroll
      for (int nt_ = 0; nt_ < 2; ++nt_) {
        float pcv = pc[i][nt_];
        #pragma unroll
        for (int j = 0; j < 4; ++j) {
          int b = (mt_ * 2 + nt_) * 4 + j;
          float Sv = S[mt_][nt_][j];
          float E  = __expf(Sv * invT);            // exp(S/T)
          float g1 = E * ei;
          float t1 = 1.0f - 2.0f / (__expf(2.0f * g1) + 1.0f);  // tanh(g1)
          float g2 = di / E;                        // e * exp((1-S)/T)
          float t2 = 1.0f - 2.0f / (__expf(2.0f * g2) + 1.0f);  // tanh(g2)
          float v  = ((mem >> b) & 1) ? t1 * t2 : t1;
          acc[mt_][nt_][j] += ((mtm >> b) & 1) ? v * pcv : 0.0f;
        }
      }
    }
  }

  // ---- store ----
  #pragma unroll
  for (int mt_ = 0; mt_ < 2; ++mt_) {
    #pragma unroll
    for (int nt_ = 0; nt_ < 2; ++nt_) {
      #pragma unroll
      for (int j = 0; j < 4; ++j) {
        int row = row0 + wr * 32 + mt_ * 16 + lr * 4 + j;
        int col = col0 + wc * 32 + nt_ * 16 + lc;
        out[(size_t)row * N + col] = acc[mt_][nt_][j];
      }
    }
  }
}

extern "C" void kernel_launch(void* const* d_in, const int* in_sizes, int n_in,
                              void* d_out, int out_size, void* d_ws, size_t ws_size,
                              hipStream_t stream) {
  const float* attributes = (const float*)d_in[0];
  const float* edges      = (const float*)d_in[1];
  const float* two_hop    = (const float*)d_in[2];
  const float* persona    = (const float*)d_in[3];
  const float* Tp         = (const float*)d_in[4];
  const float* ep         = (const float*)d_in[5];
  const float* rp         = (const float*)d_in[6];
  const float* Wp         = (const float*)d_in[7];
  const int*   timesP     = (const int*)d_in[8];
  float* out = (float*)d_out;

  // workspace: Fnb [KP][N][D] bf16 (1 MB), ME (512 KB), MT (512 KB)
  ushort* Fnb = (ushort*)d_ws;
  u64* ME = (u64*)((char*)d_ws + (size_t)KP * N * D * 2);
  u64* MT = ME + (size_t)N * 32;

  row_kernel<<<N, 256, 0, stream>>>(attributes, edges, two_hop, persona,
                                    timesP, rp, Wp, Fnb, ME, MT, out);
  edge_kernel<<<dim3(N / 64, N / 64), 256, 0, stream>>>(
      ME, MT, persona, timesP, Tp, ep, Fnb, out);
}

// Round 5
// 34.283 us; speedup vs baseline: 1.3563x; 1.3563x over previous
//
#include <hip/hip_runtime.h>
#include <math.h>

#define N 2048
#define D 64
#define KP 4

typedef unsigned int uint;
typedef unsigned short ushort;
typedef unsigned long long u64;
typedef __attribute__((ext_vector_type(8))) short bf16x8;
typedef __attribute__((ext_vector_type(4))) float f32x4;
typedef __attribute__((ext_vector_type(4))) uint uint4v;

// float -> bf16 round-to-nearest-even
__device__ __forceinline__ ushort f2bf(float f) {
  uint u = __builtin_bit_cast(uint, f);
  u += 0x7FFFu + ((u >> 16) & 1u);
  return (ushort)(u >> 16);
}

// tanh for x>0 via Pade(5,4) with clamp at 4; abs err <= 2.4e-3
__device__ __forceinline__ float tanh_pade(float x) {
  float y = fminf(x, 4.0f);
  float y2 = y * y;
  float p = y * (945.0f + y2 * (105.0f + y2));
  float q = 945.0f + y2 * (420.0f + y2 * 15.0f);
  return p * __builtin_amdgcn_rcpf(q);
}

// Mask layout: per row, 8 chunks of 256 cols; each chunk = 4 u64 words.
// Bit l of word j  <->  col = chunk*256 + 4*l + j.

// ---------------- Kernel 1: masks + EA + feat + Fn_bf16 + attr_prob -------
__global__ __launch_bounds__(256) void row_kernel(
    const float* __restrict__ attr, const float* __restrict__ edges,
    const float* __restrict__ two_hop, const float* __restrict__ persona,
    const int* __restrict__ timesP, const float* __restrict__ rp,
    const float* __restrict__ Wp, ushort* __restrict__ Fnb,
    u64* __restrict__ ME, u64* __restrict__ MT, float* __restrict__ out)
{
  __shared__ float part[4][64];

  int t = threadIdx.x;
  int w = t >> 6, l = t & 63;
  int row = blockIdx.x;

  const float4* erow4 = reinterpret_cast<const float4*>(edges + (size_t)row * N);
  const float4* trow4 = reinterpret_cast<const float4*>(two_hop + (size_t)row * N);

  u64 mw[2][4];
  #pragma unroll
  for (int cc = 0; cc < 2; ++cc) {
    int chunk = 2 * w + cc;
    float4 ev = erow4[chunk * 64 + l];
    float4 tv = trow4[chunk * 64 + l];
    int colb = chunk * 256 + 4 * l;
    float evs[4] = {ev.x, ev.y, ev.z, ev.w};
    float tvs[4] = {tv.x, tv.y, tv.z, tv.w};
    #pragma unroll
    for (int jj = 0; jj < 4; ++jj) {
      bool eb = evs[jj] != 0.0f;
      u64 meb = __ballot(eb);
      u64 mtb = __ballot((eb || tvs[jj] != 0.0f) && (colb + jj != row));
      mw[cc][jj] = meb;
      if (l == jj) {
        ME[(size_t)row * 32 + chunk * 4 + jj] = meb;
        MT[(size_t)row * 32 + chunk * 4 + jj] = mtb;
      }
    }
  }

  // EA gather: lane l = dimension d
  float acc = 0.0f;
  #pragma unroll
  for (int cc = 0; cc < 2; ++cc) {
    #pragma unroll
    for (int jj = 0; jj < 4; ++jj) {
      u64 word = mw[cc][jj];
      int base = (2 * w + cc) * 256 + jj;
      while (word) {
        int b = __builtin_ctzll(word);
        word &= word - 1;
        acc += attr[(size_t)(base + 4 * b) * D + l];
      }
    }
  }
  part[w][l] = acc;
  __syncthreads();
  float ea = part[0][l] + part[1][l] + part[2][l] + part[3][l];
  __syncthreads();   // before part reuse

  // wave w handles persona component i = w
  float a = attr[(size_t)row * D + l];
  float ri = rp[w], Wi = Wp[w];
  float nf = ri * a + ea * Wi * (1.0f - ri);
  float ss = nf * nf;
  #pragma unroll
  for (int off = 32; off; off >>= 1) ss += __shfl_xor(ss, off);
  float inv = rsqrtf(ss);
  Fnb[((size_t)w * N + row) * D + l] = f2bf(nf * inv);

  int times = timesP[0];
  float p = persona[((size_t)times * N + row) * KP + w];
  float sig = 1.0f / (1.0f + __expf(-nf));
  part[w][l] = p * sig;
  __syncthreads();
  if (w == 0) {
    out[(size_t)N * N + (size_t)row * D + l] =
        part[0][l] + part[1][l] + part[2][l] + part[3][l];
  }
}

// ---------------- Kernel 2: edges_prob via bf16 MFMA ----------------
__device__ __forceinline__ bf16x8 frag_read(const ushort* buf, int prow, int dbyte) {
  int off = prow * 128 + (dbyte ^ ((prow & 7) << 4));
  return *(const bf16x8*)((const char*)buf + off);
}

__global__ __launch_bounds__(256, 4) void edge_kernel(
    const u64* __restrict__ ME, const u64* __restrict__ MT,
    const float* __restrict__ persona, const int* __restrict__ timesP,
    const float* __restrict__ Tp, const float* __restrict__ ep,
    const ushort* __restrict__ Fnb, float* __restrict__ out)
{
  __shared__ ushort Ab[64 * 64];
  __shared__ ushort Bb[64 * 64];
  __shared__ u64 meL[64][4], mtL[64][4];

  int t = threadIdx.x;
  int w = t >> 6, l = t & 63;
  int wr = w >> 1, wc = w & 1;
  int lr = l >> 4, lc = l & 15;
  int row0 = blockIdx.y * 64;
  int col0 = blockIdx.x * 64;
  int times = timesP[0];

  // stage mask words: 512 u64, each thread loads 2
  {
    int rr = t >> 2, jj = t & 3;
    int cb4 = (col0 >> 8) * 4;
    meL[rr][jj] = ME[(size_t)(row0 + rr) * 32 + cb4 + jj];
    mtL[rr][jj] = MT[(size_t)(row0 + rr) * 32 + cb4 + jj];
  }
  __syncthreads();

  // ---- masks for my 16 elements (MFMA C/D layout) ----
  uint mem = 0, mtm = 0;
  {
    int j = lc & 3;
    int s0 = ((col0 & 255) >> 2) + wc * 8 + (lc >> 2);
    #pragma unroll
    for (int mt_ = 0; mt_ < 2; ++mt_) {
      #pragma unroll
      for (int jr = 0; jr < 4; ++jr) {
        int rowl = wr * 32 + mt_ * 16 + lr * 4 + jr;
        u64 mew = meL[rowl][j], mtw = mtL[rowl][j];
        #pragma unroll
        for (int nt_ = 0; nt_ < 2; ++nt_) {
          int bp = s0 + nt_ * 4;
          int b = (mt_ * 2 + nt_) * 4 + jr;
          mem |= (uint)((mew >> bp) & 1ull) << b;
          mtm |= (uint)((mtw >> bp) & 1ull) << b;
        }
      }
    }
  }

  // ---- persona for my 2 column tiles, all 4 components ----
  float pc[KP][2];
  #pragma unroll
  for (int i = 0; i < KP; ++i) {
    #pragma unroll
    for (int nt_ = 0; nt_ < 2; ++nt_) {
      int col = col0 + wc * 32 + nt_ * 16 + lc;
      pc[i][nt_] = persona[((size_t)times * N + col) * KP + i];
    }
  }

  f32x4 acc[2][2] = {};

  #pragma unroll
  for (int i = 0; i < KP; ++i) {
    __syncthreads();
    // ---- stage Fn panels (bf16, swizzled) ----
    {
      int r = t >> 2, q = t & 3;
      uint sw = (uint)((r & 7) << 4);
      const char* srcA = (const char*)(Fnb + ((size_t)i * N + row0 + r) * D);
      uint4v a0 = *(const uint4v*)(srcA + q * 32);
      uint4v a1 = *(const uint4v*)(srcA + q * 32 + 16);
      char* dstA = (char*)Ab + r * 128;
      *(uint4v*)(dstA + ((q * 32) ^ sw)) = a0;
      *(uint4v*)(dstA + ((q * 32 + 16) ^ sw)) = a1;
      const char* srcB = (const char*)(Fnb + ((size_t)i * N + col0 + r) * D);
      uint4v b0 = *(const uint4v*)(srcB + q * 32);
      uint4v b1 = *(const uint4v*)(srcB + q * 32 + 16);
      char* dstB = (char*)Bb + r * 128;
      *(uint4v*)(dstB + ((q * 32) ^ sw)) = b0;
      *(uint4v*)(dstB + ((q * 32 + 16) ^ sw)) = b1;
    }
    __syncthreads();

    // ---- S quadrant via MFMA ----
    f32x4 S[2][2] = {};
    #pragma unroll
    for (int ks = 0; ks < 2; ++ks) {
      int dbyte = ks * 64 + lr * 16;
      bf16x8 a0 = frag_read(Ab, wr * 32 + lc, dbyte);
      bf16x8 a1 = frag_read(Ab, wr * 32 + 16 + lc, dbyte);
      bf16x8 b0 = frag_read(Bb, wc * 32 + lc, dbyte);
      bf16x8 b1 = frag_read(Bb, wc * 32 + 16 + lc, dbyte);
      S[0][0] = __builtin_amdgcn_mfma_f32_16x16x32_bf16(a0, b0, S[0][0], 0, 0, 0);
      S[0][1] = __builtin_amdgcn_mfma_f32_16x16x32_bf16(a0, b1, S[0][1], 0, 0, 0);
      S[1][0] = __builtin_amdgcn_mfma_f32_16x16x32_bf16(a1, b0, S[1][0], 0, 0, 0);
      S[1][1] = __builtin_amdgcn_mfma_f32_16x16x32_bf16(a1, b1, S[1][1], 0, 0, 0);
    }

    // ---- nonlinearity: phased dense conn + conditional delete ----
    float invT = 1.0f / Tp[i];
    float ei = ep[i];
    float di = ei * __expf(invT);   // e * exp(1/T)
    #pragma unroll
    for (int mt_ = 0; mt_ < 2; ++mt_) {
      #pragma unroll
      for (int nt_ = 0; nt_ < 2; ++nt_) {
        float pcv = pc[i][nt_];
        int bb = (mt_ * 2 + nt_) * 4;
        float E[4], t1[4];
        #pragma unroll
        for (int j = 0; j < 4; ++j) E[j] = __expf(S[mt_][nt_][j] * invT);
        #pragma unroll
        for (int j = 0; j < 4; ++j) t1[j] = tanh_pade(E[j] * ei);
        #pragma unroll
        for (int j = 0; j < 4; ++j) {
          if ((mem >> (bb + j)) & 1) {
            t1[j] *= tanh_pade(di * __builtin_amdgcn_rcpf(E[j]));
          }
        }
        #pragma unroll
        for (int j = 0; j < 4; ++j) {
          acc[mt_][nt_][j] += ((mtm >> (bb + j)) & 1) ? t1[j] * pcv : 0.0f;
        }
      }
    }
  }

  // ---- store ----
  #pragma unroll
  for (int mt_ = 0; mt_ < 2; ++mt_) {
    #pragma unroll
    for (int nt_ = 0; nt_ < 2; ++nt_) {
      #pragma unroll
      for (int j = 0; j < 4; ++j) {
        int row = row0 + wr * 32 + mt_ * 16 + lr * 4 + j;
        int col = col0 + wc * 32 + nt_ * 16 + lc;
        out[(size_t)row * N + col] = acc[mt_][nt_][j];
      }
    }
  }
}

extern "C" void kernel_launch(void* const* d_in, const int* in_sizes, int n_in,
                              void* d_out, int out_size, void* d_ws, size_t ws_size,
                              hipStream_t stream) {
  const float* attributes = (const float*)d_in[0];
  const float* edges      = (const float*)d_in[1];
  const float* two_hop    = (const float*)d_in[2];
  const float* persona    = (const float*)d_in[3];
  const float* Tp         = (const float*)d_in[4];
  const float* ep         = (const float*)d_in[5];
  const float* rp         = (const float*)d_in[6];
  const float* Wp         = (const float*)d_in[7];
  const int*   timesP     = (const int*)d_in[8];
  float* out = (float*)d_out;

  // workspace: Fnb [KP][N][D] bf16 (1 MB), ME (512 KB), MT (512 KB)
  ushort* Fnb = (ushort*)d_ws;
  u64* ME = (u64*)((char*)d_ws + (size_t)KP * N * D * 2);
  u64* MT = ME + (size_t)N * 32;

  row_kernel<<<N, 256, 0, stream>>>(attributes, edges, two_hop, persona,
                                    timesP, rp, Wp, Fnb, ME, MT, out);
  edge_kernel<<<dim3(N / 64, N / 64), 256, 0, stream>>>(
      ME, MT, persona, timesP, Tp, ep, Fnb, out);
}